// Round 1
// baseline (32.397 us; speedup 1.0000x reference)
//
#include <hip/hip_runtime.h>
#include <math.h>

// Chamfer loss, B=8, N=M=4096, D=3, fp32.
// k1: pairwise min over target chunks (2 dirs fused). k2: min-over-chunks + per-block sums.
// k3: weighted final scalar.

constexpr int BATCH = 8;
constexpr int NP    = 4096;   // points per cloud (both x and y)
constexpr int MC    = 8;      // target chunks
constexpr int MCH   = 512;    // target points per chunk
constexpr int XC    = 4;      // query chunks (1024 points each)
constexpr int KPT   = 4;      // query points per thread
constexpr int T     = 256;    // threads per block

// ws layout in floats:
//   [0,           262144)  pmin dir0 (queries = x): [b][mc][n]
//   [262144,      524288)  pmin dir1 (queries = y)
//   [524288,      524352)  64 per-block partial sums
constexpr size_t PMIN_STRIDE = (size_t)BATCH * MC * NP; // 262144
constexpr size_t PS_OFF      = 2 * PMIN_STRIDE;          // 524288

__global__ __launch_bounds__(T) void chamfer_partial(
    const float* __restrict__ x, const float* __restrict__ y,
    float* __restrict__ ws)
{
    const int bid = blockIdx.x;          // 512 blocks
    const int dir = bid >> 8;            // 0: query=x target=y ; 1: swapped
    const int r   = bid & 255;
    const int b   = r >> 5;              // batch
    const int xc  = (r >> 3) & 3;        // query chunk
    const int mc  = r & 7;               // target chunk

    const float* q = dir ? y : x;
    const float* t = dir ? x : y;

    __shared__ float4 ty[MCH];           // (t0, t1, t2, |t|^2)  8 KB
    const int tid = threadIdx.x;

    const float* tb = t + (size_t)(b * NP + mc * MCH) * 3;
    for (int j = tid; j < MCH; j += T) {
        float y0 = tb[3 * j + 0];
        float y1 = tb[3 * j + 1];
        float y2 = tb[3 * j + 2];
        ty[j] = make_float4(y0, y1, y2, fmaf(y0, y0, fmaf(y1, y1, y2 * y2)));
    }

    // Load 4 query points (12 consecutive floats, 16B-aligned) as 3x float4.
    const int n0 = b * NP + xc * 1024 + tid * KPT;
    const float4* qb = reinterpret_cast<const float4*>(q + (size_t)n0 * 3);
    float4 qa = qb[0], q1 = qb[1], q2 = qb[2];
    float px[KPT][3] = {
        {qa.x, qa.y, qa.z},
        {qa.w, q1.x, q1.y},
        {q1.z, q1.w, q2.x},
        {q2.y, q2.z, q2.w},
    };
    float xn[KPT][3], x2s[KPT];
    #pragma unroll
    for (int k = 0; k < KPT; ++k) {
        x2s[k] = fmaf(px[k][0], px[k][0], fmaf(px[k][1], px[k][1], px[k][2] * px[k][2]));
        #pragma unroll
        for (int d = 0; d < 3; ++d) xn[k][d] = -2.0f * px[k][d];
    }

    __syncthreads();

    float mn[KPT] = {INFINITY, INFINITY, INFINITY, INFINITY};
    #pragma unroll 8
    for (int j = 0; j < MCH; ++j) {
        float4 tv = ty[j];               // wave-uniform -> LDS broadcast
        #pragma unroll
        for (int k = 0; k < KPT; ++k) {
            float d = x2s[k] + tv.w;     // x^2 + y^2
            d = fmaf(xn[k][0], tv.x, d); // - 2 x.y
            d = fmaf(xn[k][1], tv.y, d);
            d = fmaf(xn[k][2], tv.z, d);
            mn[k] = fminf(mn[k], d);
        }
    }

    float4 out;
    out.x = fmaxf(mn[0], 0.0f);
    out.y = fmaxf(mn[1], 0.0f);
    out.z = fmaxf(mn[2], 0.0f);
    out.w = fmaxf(mn[3], 0.0f);

    float* pm = ws + (size_t)dir * PMIN_STRIDE
                   + ((size_t)(b * MC + mc)) * NP
                   + (size_t)xc * 1024 + (size_t)tid * KPT;
    *reinterpret_cast<float4*>(pm) = out;
}

__global__ __launch_bounds__(T) void chamfer_combine(
    const float* __restrict__ ws, float* __restrict__ ps)
{
    const int bid = blockIdx.x;          // 64 blocks: dir(2) x b(8) x nq(4)
    const int dir = bid >> 5;
    const int b   = (bid >> 2) & 7;
    const int nq  = bid & 3;
    const int tid = threadIdx.x;

    const float* base = ws + (size_t)dir * PMIN_STRIDE + (size_t)b * MC * NP;

    float sum = 0.0f;
    #pragma unroll
    for (int i = 0; i < 4; ++i) {
        const int n = nq * 1024 + i * 256 + tid;
        float v = INFINITY;
        #pragma unroll
        for (int m = 0; m < MC; ++m) v = fminf(v, base[(size_t)m * NP + n]);
        sum += v;
    }

    // fixed-order block reduction: wave shuffle then 4 wave leaders via LDS
    for (int off = 32; off; off >>= 1) sum += __shfl_down(sum, off, 64);
    __shared__ float red[4];
    if ((tid & 63) == 0) red[tid >> 6] = sum;
    __syncthreads();
    if (tid == 0) ps[bid] = (red[0] + red[1]) + (red[2] + red[3]);
}

__global__ void chamfer_final(
    const float* __restrict__ ps, const float* __restrict__ w,
    float* __restrict__ out)
{
    const int l = threadIdx.x;           // 64 lanes
    float v = ps[l];
    const int b = (l >> 2) & 7;
    float acc = v * w[b] * (1.0f / ((float)NP * (float)BATCH));
    for (int off = 32; off; off >>= 1) acc += __shfl_down(acc, off, 64);
    if (l == 0) out[0] = acc;
}

extern "C" void kernel_launch(void* const* d_in, const int* in_sizes, int n_in,
                              void* d_out, int out_size, void* d_ws, size_t ws_size,
                              hipStream_t stream) {
    const float* x = (const float*)d_in[0];   // (8, 4096, 3)
    const float* y = (const float*)d_in[1];   // (8, 4096, 3)
    const float* w = (const float*)d_in[2];   // (8,)
    float* out = (float*)d_out;
    float* ws  = (float*)d_ws;

    chamfer_partial<<<2 * BATCH * XC * MC, T, 0, stream>>>(x, y, ws);
    chamfer_combine<<<64, T, 0, stream>>>(ws, ws + PS_OFF);
    chamfer_final<<<1, 64, 0, stream>>>(ws + PS_OFF, w, out);
}

// Round 2
// 30.424 us; speedup vs baseline: 1.0649x; 1.0649x over previous
//
#include <hip/hip_runtime.h>
#include <math.h>

// Chamfer loss, B=8, N=M=4096, D=3, fp32.
// k1: pairwise min over target chunks (2 dirs fused), 4 VALU ops/pair
//     (|x|^2 deferred to epilogue), KPT=8 queries/thread so each LDS
//     broadcast feeds 32 VALU ops.
// k2: min-over-16-chunks + per-block sums. k3: weighted final scalar.

constexpr int BATCH = 8;
constexpr int NP    = 4096;   // points per cloud
constexpr int MC    = 16;     // target chunks
constexpr int MCH   = 256;    // target points per chunk
constexpr int KPT   = 8;      // query points per thread
constexpr int T     = 256;    // threads per block
// queries per block = T*KPT = 2048 -> XC = 2 query chunks

// ws layout in floats:
//   [0,            524288)  pmin dir0 (queries = x): [b][mc][n]
//   [524288,      1048576)  pmin dir1 (queries = y)
//   [1048576,     1048640)  64 per-block partial sums
constexpr size_t PMIN_STRIDE = (size_t)BATCH * MC * NP; // 524288
constexpr size_t PS_OFF      = 2 * PMIN_STRIDE;         // 1048576

__global__ __launch_bounds__(T) void chamfer_partial(
    const float* __restrict__ x, const float* __restrict__ y,
    float* __restrict__ ws)
{
    const int bid = blockIdx.x;          // 512 blocks
    const int dir = bid >> 8;            // 0: query=x target=y ; 1: swapped
    const int r   = bid & 255;
    const int b   = r >> 5;              // batch
    const int xc  = (r >> 4) & 1;        // query chunk (2048 queries each)
    const int mc  = r & 15;              // target chunk (256 targets each)

    const float* q = dir ? y : x;
    const float* t = dir ? x : y;

    __shared__ float4 ty[MCH];           // (t0, t1, t2, |t|^2)  4 KB
    const int tid = threadIdx.x;

    const float* tb = t + (size_t)(b * NP + mc * MCH) * 3;
    {   // T == MCH: one target per thread
        float t0 = tb[3 * tid + 0];
        float t1 = tb[3 * tid + 1];
        float t2 = tb[3 * tid + 2];
        ty[tid] = make_float4(t0, t1, t2, fmaf(t0, t0, fmaf(t1, t1, t2 * t2)));
    }

    // Load 8 query points (24 consecutive floats, 16B-aligned) as 6x float4.
    const int n0 = b * NP + xc * 2048 + tid * KPT;
    const float4* qb = reinterpret_cast<const float4*>(q + (size_t)n0 * 3);
    float4 v0 = qb[0], v1 = qb[1], v2 = qb[2], v3 = qb[3], v4 = qb[4], v5 = qb[5];
    float px[KPT][3] = {
        {v0.x, v0.y, v0.z}, {v0.w, v1.x, v1.y},
        {v1.z, v1.w, v2.x}, {v2.y, v2.z, v2.w},
        {v3.x, v3.y, v3.z}, {v3.w, v4.x, v4.y},
        {v4.z, v4.w, v5.x}, {v5.y, v5.z, v5.w},
    };
    float xn[KPT][3], x2s[KPT], mn[KPT];
    #pragma unroll
    for (int k = 0; k < KPT; ++k) {
        x2s[k] = fmaf(px[k][0], px[k][0], fmaf(px[k][1], px[k][1], px[k][2] * px[k][2]));
        #pragma unroll
        for (int d = 0; d < 3; ++d) xn[k][d] = -2.0f * px[k][d];
        mn[k] = INFINITY;
    }

    __syncthreads();

    // min over j of d' = |t|^2 - 2 q.t   (|q|^2 added in epilogue)
    #pragma unroll 4
    for (int j = 0; j < MCH; ++j) {
        float4 tv = ty[j];               // wave-uniform -> LDS broadcast, all-VGPR result
        #pragma unroll
        for (int k = 0; k < KPT; ++k) {
            float d = fmaf(xn[k][2], tv.z, tv.w);
            d = fmaf(xn[k][1], tv.y, d);
            d = fmaf(xn[k][0], tv.x, d);
            mn[k] = fminf(mn[k], d);
        }
    }

    float4 o0, o1;
    o0.x = fmaxf(x2s[0] + mn[0], 0.0f);
    o0.y = fmaxf(x2s[1] + mn[1], 0.0f);
    o0.z = fmaxf(x2s[2] + mn[2], 0.0f);
    o0.w = fmaxf(x2s[3] + mn[3], 0.0f);
    o1.x = fmaxf(x2s[4] + mn[4], 0.0f);
    o1.y = fmaxf(x2s[5] + mn[5], 0.0f);
    o1.z = fmaxf(x2s[6] + mn[6], 0.0f);
    o1.w = fmaxf(x2s[7] + mn[7], 0.0f);

    float* pm = ws + (size_t)dir * PMIN_STRIDE
                   + ((size_t)(b * MC + mc)) * NP
                   + (size_t)xc * 2048 + (size_t)tid * KPT;
    reinterpret_cast<float4*>(pm)[0] = o0;
    reinterpret_cast<float4*>(pm)[1] = o1;
}

__global__ __launch_bounds__(T) void chamfer_combine(
    const float* __restrict__ ws, float* __restrict__ ps)
{
    const int bid = blockIdx.x;          // 64 blocks: dir(2) x b(8) x nq(4)
    const int dir = bid >> 5;
    const int b   = (bid >> 2) & 7;
    const int nq  = bid & 3;
    const int tid = threadIdx.x;

    const float* base = ws + (size_t)dir * PMIN_STRIDE + (size_t)b * MC * NP;

    float sum = 0.0f;
    #pragma unroll
    for (int i = 0; i < 4; ++i) {
        const int n = nq * 1024 + i * 256 + tid;
        float v = INFINITY;
        #pragma unroll
        for (int m = 0; m < MC; ++m) v = fminf(v, base[(size_t)m * NP + n]);
        sum += v;
    }

    // fixed-order block reduction: wave shuffle then 4 wave leaders via LDS
    for (int off = 32; off; off >>= 1) sum += __shfl_down(sum, off, 64);
    __shared__ float red[4];
    if ((tid & 63) == 0) red[tid >> 6] = sum;
    __syncthreads();
    if (tid == 0) ps[bid] = (red[0] + red[1]) + (red[2] + red[3]);
}

__global__ void chamfer_final(
    const float* __restrict__ ps, const float* __restrict__ w,
    float* __restrict__ out)
{
    const int l = threadIdx.x;           // 64 lanes
    float v = ps[l];
    const int b = (l >> 2) & 7;
    float acc = v * w[b] * (1.0f / ((float)NP * (float)BATCH));
    for (int off = 32; off; off >>= 1) acc += __shfl_down(acc, off, 64);
    if (l == 0) out[0] = acc;
}

extern "C" void kernel_launch(void* const* d_in, const int* in_sizes, int n_in,
                              void* d_out, int out_size, void* d_ws, size_t ws_size,
                              hipStream_t stream) {
    const float* x = (const float*)d_in[0];   // (8, 4096, 3)
    const float* y = (const float*)d_in[1];   // (8, 4096, 3)
    const float* w = (const float*)d_in[2];   // (8,)
    float* out = (float*)d_out;
    float* ws  = (float*)d_ws;

    chamfer_partial<<<512, T, 0, stream>>>(x, y, ws);
    chamfer_combine<<<64, T, 0, stream>>>(ws, ws + PS_OFF);
    chamfer_final<<<1, 64, 0, stream>>>(ws + PS_OFF, w, out);
}